// Round 7
// baseline (527.747 us; speedup 1.0000x reference)
//
#include <hip/hip_runtime.h>

#define N_NODES 50000
#define N_EDGES 1600000
#define D_IN    128
#define D_EDGE  64
#define D_NODE  128
#define NB      32      // nodes per block in GEMM kernels

__device__ __forceinline__ float4 fma4(float s, float4 w, float4 a) {
    a.x = fmaf(s, w.x, a.x); a.y = fmaf(s, w.y, a.y);
    a.z = fmaf(s, w.z, a.z); a.w = fmaf(s, w.w, a.w);
    return a;
}

// ---------------------------------------------------------------------------
// Kernel 1: projR = relu(x @ W_fs + b_fs)   [N_NODES, 64]
// Register-tiled; x tile in LDS (padded rows), W via coalesced float4.
// ---------------------------------------------------------------------------
__global__ __launch_bounds__(256)
void proj_relu_kernel(const float* __restrict__ x,
                      const float* __restrict__ W,   // [128][64]
                      const float* __restrict__ b,   // [64]
                      float* __restrict__ out) {     // [N][64]
    __shared__ float xs[NB][D_IN + 4];
    const int tid = threadIdx.x;
    const int nb0 = blockIdx.x * NB;

    const float4* xv = (const float4*)x;
    for (int i = tid; i < NB * 32; i += 256) {
        int nl = i >> 5, c = i & 31;
        int n = nb0 + nl;
        float4 v = make_float4(0.f, 0.f, 0.f, 0.f);
        if (n < N_NODES) v = xv[(size_t)n * 32 + c];
        *(float4*)&xs[nl][c * 4] = v;
    }
    __syncthreads();

    const int fq = tid & 15;
    const int slot = tid >> 4;
    const float4* W4 = (const float4*)W;
    float4 bb = ((const float4*)b)[fq];
    float4 acc0 = bb, acc1 = bb;

#pragma unroll 8
    for (int k0 = 0; k0 < D_IN; k0 += 4) {
        float4 w0 = W4[(k0 + 0) * 16 + fq];
        float4 w1 = W4[(k0 + 1) * 16 + fq];
        float4 w2 = W4[(k0 + 2) * 16 + fq];
        float4 w3 = W4[(k0 + 3) * 16 + fq];
        float4 xa = *(const float4*)&xs[slot][k0];
        float4 xb = *(const float4*)&xs[slot + 16][k0];
        acc0 = fma4(xa.x, w0, acc0); acc0 = fma4(xa.y, w1, acc0);
        acc0 = fma4(xa.z, w2, acc0); acc0 = fma4(xa.w, w3, acc0);
        acc1 = fma4(xb.x, w0, acc1); acc1 = fma4(xb.y, w1, acc1);
        acc1 = fma4(xb.z, w2, acc1); acc1 = fma4(xb.w, w3, acc1);
    }

    float4* out4 = (float4*)out;
    int na = nb0 + slot, nbn = nb0 + slot + 16;
    if (na < N_NODES) {
        float4 r = make_float4(fmaxf(acc0.x, 0.f), fmaxf(acc0.y, 0.f),
                               fmaxf(acc0.z, 0.f), fmaxf(acc0.w, 0.f));
        out4[(size_t)na * 16 + fq] = r;
    }
    if (nbn < N_NODES) {
        float4 r = make_float4(fmaxf(acc1.x, 0.f), fmaxf(acc1.y, 0.f),
                               fmaxf(acc1.z, 0.f), fmaxf(acc1.w, 0.f));
        out4[(size_t)nbn * 16 + fq] = r;
    }
}

// ---------------------------------------------------------------------------
// CSR build, step 1: per-receiver degree histogram (counts pre-zeroed).
// int atomics on a 200 KB L2-resident array; 4 edges/thread via int4 loads.
// ---------------------------------------------------------------------------
__global__ __launch_bounds__(256)
void hist_kernel(const int* __restrict__ receivers, int* __restrict__ counts) {
    int i = (blockIdx.x * blockDim.x + threadIdx.x) * 4;
    if (i >= N_EDGES) return;
    int4 r = *(const int4*)(receivers + i);
    atomicAdd(&counts[r.x], 1);
    atomicAdd(&counts[r.y], 1);
    atomicAdd(&counts[r.z], 1);
    atomicAdd(&counts[r.w], 1);
}

// ---------------------------------------------------------------------------
// CSR build, step 2: exclusive scan of 50K counts in one 1024-thread block
// (thread owns a 49-element chunk; Hillis-Steele over chunk sums in LDS).
// Writes offsets[0..N] plus a cursor copy for the fill pass.
// ---------------------------------------------------------------------------
__global__ __launch_bounds__(1024)
void scan_kernel(const int* __restrict__ counts,
                 int* __restrict__ offsets,
                 int* __restrict__ cursor) {
    __shared__ int sums[1024];
    const int t = threadIdx.x;
    const int CH = (N_NODES + 1023) / 1024;          // 49
    int lo = t * CH;
    int hi = lo + CH; if (hi > N_NODES) hi = N_NODES;
    if (lo > N_NODES) lo = N_NODES;
    int s = 0;
    for (int i = lo; i < hi; ++i) s += counts[i];
    sums[t] = s;
    __syncthreads();
    for (int d = 1; d < 1024; d <<= 1) {
        int v = (t >= d) ? sums[t - d] : 0;
        __syncthreads();
        sums[t] += v;
        __syncthreads();
    }
    int run = (t == 0) ? 0 : sums[t - 1];            // exclusive base
    for (int i = lo; i < hi; ++i) {
        int c = counts[i];
        offsets[i] = run;
        cursor[i]  = run;
        run += c;
    }
    if (t == 1023) offsets[N_NODES] = run;           // == N_EDGES
}

// ---------------------------------------------------------------------------
// CSR build, step 3: bucket-fill senders sorted by receiver.
// 4 edges/thread, int4 index loads. Order within a bucket is nondeterministic
// but max is order-independent.
// ---------------------------------------------------------------------------
__global__ __launch_bounds__(256)
void fill_kernel(const int* __restrict__ senders,
                 const int* __restrict__ receivers,
                 int* __restrict__ cursor,
                 int* __restrict__ sortedS) {
    int i = (blockIdx.x * blockDim.x + threadIdx.x) * 4;
    if (i >= N_EDGES) return;
    int4 r = *(const int4*)(receivers + i);
    int4 s = *(const int4*)(senders + i);
    sortedS[atomicAdd(&cursor[r.x], 1)] = s.x;
    sortedS[atomicAdd(&cursor[r.y], 1)] = s.y;
    sortedS[atomicAdd(&cursor[r.z], 1)] = s.z;
    sortedS[atomicAdd(&cursor[r.w], 1)] = s.w;
}

// ---------------------------------------------------------------------------
// Kernel 2: atomic-free gather-max. One wave per node, lane = feature.
// Edge indices loaded 64-wide coalesced, broadcast via __shfl; projR row
// loads 8 deep for MLP. agg written exactly once (12.8 MB streaming).
// acc=0 start == reference's empty-segment->0 (post-relu values >= 0).
// ---------------------------------------------------------------------------
__global__ __launch_bounds__(256)
void gather_max_kernel(const float* __restrict__ projR,
                       const int*   __restrict__ offsets,
                       const int*   __restrict__ sortedS,
                       float* __restrict__ agg) {
    int tid  = blockIdx.x * blockDim.x + threadIdx.x;
    int n    = tid >> 6;
    int lane = tid & 63;
    if (n >= N_NODES) return;
    int beg = offsets[n];
    int end = offsets[n + 1];
    float acc = 0.0f;
    for (int base = beg; base < end; base += 64) {
        int len = end - base; if (len > 64) len = 64;
        int idx = 0;
        if (lane < len) idx = sortedS[base + lane];   // coalesced 256B load
        int i = 0;
        for (; i + 8 <= len; i += 8) {
            float v0 = projR[(size_t)__shfl(idx, i)     * D_EDGE + lane];
            float v1 = projR[(size_t)__shfl(idx, i + 1) * D_EDGE + lane];
            float v2 = projR[(size_t)__shfl(idx, i + 2) * D_EDGE + lane];
            float v3 = projR[(size_t)__shfl(idx, i + 3) * D_EDGE + lane];
            float v4 = projR[(size_t)__shfl(idx, i + 4) * D_EDGE + lane];
            float v5 = projR[(size_t)__shfl(idx, i + 5) * D_EDGE + lane];
            float v6 = projR[(size_t)__shfl(idx, i + 6) * D_EDGE + lane];
            float v7 = projR[(size_t)__shfl(idx, i + 7) * D_EDGE + lane];
            float m0 = fmaxf(fmaxf(v0, v1), fmaxf(v2, v3));
            float m1 = fmaxf(fmaxf(v4, v5), fmaxf(v6, v7));
            acc = fmaxf(acc, fmaxf(m0, m1));
        }
        for (; i < len; ++i) {
            int s = __shfl(idx, i);
            acc = fmaxf(acc, projR[(size_t)s * D_EDGE + lane]);
        }
    }
    agg[(size_t)n * D_EDGE + lane] = acc;
}

// ---------------------------------------------------------------------------
// Kernel 3: out = x @ W_gn + agg @ W_gin + (b_gn + b_gin)   [N_NODES, 128]
// ---------------------------------------------------------------------------
__global__ __launch_bounds__(256)
void node_out_kernel(const float* __restrict__ x,     // [N][128]
                     const float* __restrict__ W_gn,  // [128][128]
                     const float* __restrict__ b_gn,  // [128]
                     const float* __restrict__ agg,   // [N][64]
                     const float* __restrict__ W_gin, // [64][128]
                     const float* __restrict__ b_gin, // [128]
                     float* __restrict__ out) {       // [N][128]
    __shared__ float xs[NB][D_IN + 4];
    __shared__ float as_[NB][D_EDGE + 4];
    const int tid = threadIdx.x;
    const int nb0 = blockIdx.x * NB;

    const float4* xv = (const float4*)x;
    for (int i = tid; i < NB * 32; i += 256) {
        int nl = i >> 5, c = i & 31;
        int n = nb0 + nl;
        float4 v = make_float4(0.f, 0.f, 0.f, 0.f);
        if (n < N_NODES) v = xv[(size_t)n * 32 + c];
        *(float4*)&xs[nl][c * 4] = v;
    }
    const float4* av = (const float4*)agg;
    for (int i = tid; i < NB * 16; i += 256) {
        int nl = i >> 4, c = i & 15;
        int n = nb0 + nl;
        float4 v = make_float4(0.f, 0.f, 0.f, 0.f);
        if (n < N_NODES) v = av[(size_t)n * 16 + c];
        *(float4*)&as_[nl][c * 4] = v;
    }
    __syncthreads();

    const int fq = tid & 31;
    const int slot = tid >> 5;
    const float4* Wg4 = (const float4*)W_gn;
    const float4* Wi4 = (const float4*)W_gin;
    float4 bb = ((const float4*)b_gn)[fq];
    float4 bi = ((const float4*)b_gin)[fq];
    bb.x += bi.x; bb.y += bi.y; bb.z += bi.z; bb.w += bi.w;
    float4 acc0 = bb, acc1 = bb, acc2 = bb, acc3 = bb;

#pragma unroll 4
    for (int k0 = 0; k0 < D_IN; k0 += 4) {
        float4 w0 = Wg4[(k0 + 0) * 32 + fq];
        float4 w1 = Wg4[(k0 + 1) * 32 + fq];
        float4 w2 = Wg4[(k0 + 2) * 32 + fq];
        float4 w3 = Wg4[(k0 + 3) * 32 + fq];
        float4 x0 = *(const float4*)&xs[slot][k0];
        float4 x1 = *(const float4*)&xs[slot + 8][k0];
        float4 x2 = *(const float4*)&xs[slot + 16][k0];
        float4 x3 = *(const float4*)&xs[slot + 24][k0];
        acc0 = fma4(x0.x, w0, acc0); acc0 = fma4(x0.y, w1, acc0);
        acc0 = fma4(x0.z, w2, acc0); acc0 = fma4(x0.w, w3, acc0);
        acc1 = fma4(x1.x, w0, acc1); acc1 = fma4(x1.y, w1, acc1);
        acc1 = fma4(x1.z, w2, acc1); acc1 = fma4(x1.w, w3, acc1);
        acc2 = fma4(x2.x, w0, acc2); acc2 = fma4(x2.y, w1, acc2);
        acc2 = fma4(x2.z, w2, acc2); acc2 = fma4(x2.w, w3, acc2);
        acc3 = fma4(x3.x, w0, acc3); acc3 = fma4(x3.y, w1, acc3);
        acc3 = fma4(x3.z, w2, acc3); acc3 = fma4(x3.w, w3, acc3);
    }

#pragma unroll 4
    for (int k0 = 0; k0 < D_EDGE; k0 += 4) {
        float4 w0 = Wi4[(k0 + 0) * 32 + fq];
        float4 w1 = Wi4[(k0 + 1) * 32 + fq];
        float4 w2 = Wi4[(k0 + 2) * 32 + fq];
        float4 w3 = Wi4[(k0 + 3) * 32 + fq];
        float4 x0 = *(const float4*)&as_[slot][k0];
        float4 x1 = *(const float4*)&as_[slot + 8][k0];
        float4 x2 = *(const float4*)&as_[slot + 16][k0];
        float4 x3 = *(const float4*)&as_[slot + 24][k0];
        acc0 = fma4(x0.x, w0, acc0); acc0 = fma4(x0.y, w1, acc0);
        acc0 = fma4(x0.z, w2, acc0); acc0 = fma4(x0.w, w3, acc0);
        acc1 = fma4(x1.x, w0, acc1); acc1 = fma4(x1.y, w1, acc1);
        acc1 = fma4(x1.z, w2, acc1); acc1 = fma4(x1.w, w3, acc1);
        acc2 = fma4(x2.x, w0, acc2); acc2 = fma4(x2.y, w1, acc2);
        acc2 = fma4(x2.z, w2, acc2); acc2 = fma4(x2.w, w3, acc2);
        acc3 = fma4(x3.x, w0, acc3); acc3 = fma4(x3.y, w1, acc3);
        acc3 = fma4(x3.z, w2, acc3); acc3 = fma4(x3.w, w3, acc3);
    }

    float4* out4 = (float4*)out;
    int n0 = nb0 + slot;
    if (n0 < N_NODES)      out4[(size_t)n0 * 32 + fq]        = acc0;
    if (n0 + 8 < N_NODES)  out4[(size_t)(n0 + 8) * 32 + fq]  = acc1;
    if (n0 + 16 < N_NODES) out4[(size_t)(n0 + 16) * 32 + fq] = acc2;
    if (n0 + 24 < N_NODES) out4[(size_t)(n0 + 24) * 32 + fq] = acc3;
}

// ---------------------------------------------------------------------------
extern "C" void kernel_launch(void* const* d_in, const int* in_sizes, int n_in,
                              void* d_out, int out_size, void* d_ws, size_t ws_size,
                              hipStream_t stream) {
    const float* node_features = (const float*)d_in[0];
    const float* W_fs          = (const float*)d_in[1];
    const float* b_fs          = (const float*)d_in[2];
    const float* W_gn          = (const float*)d_in[3];
    const float* b_gn          = (const float*)d_in[4];
    const float* W_gin         = (const float*)d_in[5];
    const float* b_gin         = (const float*)d_in[6];
    const int*   senders       = (const int*)d_in[7];
    const int*   receivers     = (const int*)d_in[8];
    float* out = (float*)d_out;

    // workspace layout (16B-aligned slices), ~32.6 MB total
    char* p = (char*)d_ws;
    float* projR   = (float*)p;   p += (size_t)N_NODES * D_EDGE * 4;   // 12.8 MB
    float* agg     = (float*)p;   p += (size_t)N_NODES * D_EDGE * 4;   // 12.8 MB
    int*   counts  = (int*)p;     p += (size_t)N_NODES * 4;            // 200 KB
    int*   offsets = (int*)p;     p += (size_t)(N_NODES + 4) * 4;
    int*   cursor  = (int*)p;     p += (size_t)N_NODES * 4;
    int*   sortedS = (int*)p;     p += (size_t)N_EDGES * 4;            // 6.4 MB

    // zero degree histogram (harness re-poisons ws with 0xAA every call)
    hipMemsetAsync(counts, 0, (size_t)N_NODES * sizeof(int), stream);

    {   // proj+relu
        int grid = (N_NODES + NB - 1) / NB;
        proj_relu_kernel<<<grid, 256, 0, stream>>>(node_features, W_fs, b_fs, projR);
    }
    {   // degree histogram: 4 edges/thread
        int threads = N_EDGES / 4;
        hist_kernel<<<(threads + 255) / 256, 256, 0, stream>>>(receivers, counts);
    }
    {   // exclusive scan -> offsets, cursor
        scan_kernel<<<1, 1024, 0, stream>>>(counts, offsets, cursor);
    }
    {   // bucket fill -> sortedS: 4 edges/thread
        int threads = N_EDGES / 4;
        fill_kernel<<<(threads + 255) / 256, 256, 0, stream>>>(senders, receivers,
                                                               cursor, sortedS);
    }
    {   // gather-max: one wave per node
        long long threads = (long long)N_NODES * 64;
        gather_max_kernel<<<(int)((threads + 255) / 256), 256, 0, stream>>>(
            projR, offsets, sortedS, agg);
    }
    {   // final GEMM
        int grid = (N_NODES + NB - 1) / NB;
        node_out_kernel<<<grid, 256, 0, stream>>>(node_features, W_gn, b_gn,
                                                  agg, W_gin, b_gin, out);
    }
}

// Round 10
// 332.994 us; speedup vs baseline: 1.5849x; 1.5849x over previous
//
#include <hip/hip_runtime.h>

#define N_NODES 50000
#define N_EDGES 1600000
#define D_IN    128
#define D_EDGE  64
#define D_NODE  128
#define NB      32        // nodes per block in GEMM kernels

#define NPB     49        // nodes per bucket
#define NBUCK   1021      // ceil(50000/49); bucket 1020 holds 20 nodes
#define NBLK    128       // edge-chunking blocks for hist/fill
#define I4PB    (N_EDGES / NBLK / 4)   // 3125 int4 loads per chunk

__device__ __forceinline__ float4 fma4(float s, float4 w, float4 a) {
    a.x = fmaf(s, w.x, a.x); a.y = fmaf(s, w.y, a.y);
    a.z = fmaf(s, w.z, a.z); a.w = fmaf(s, w.w, a.w);
    return a;
}

// ---------------------------------------------------------------------------
// Kernel 1: projR = relu(x @ W_fs + b_fs)   [N_NODES, 64]
// ---------------------------------------------------------------------------
__global__ __launch_bounds__(256)
void proj_relu_kernel(const float* __restrict__ x,
                      const float* __restrict__ W,   // [128][64]
                      const float* __restrict__ b,   // [64]
                      float* __restrict__ out) {     // [N][64]
    __shared__ float xs[NB][D_IN + 4];
    const int tid = threadIdx.x;
    const int nb0 = blockIdx.x * NB;

    const float4* xv = (const float4*)x;
    for (int i = tid; i < NB * 32; i += 256) {
        int nl = i >> 5, c = i & 31;
        int n = nb0 + nl;
        float4 v = make_float4(0.f, 0.f, 0.f, 0.f);
        if (n < N_NODES) v = xv[(size_t)n * 32 + c];
        *(float4*)&xs[nl][c * 4] = v;
    }
    __syncthreads();

    const int fq = tid & 15;
    const int slot = tid >> 4;
    const float4* W4 = (const float4*)W;
    float4 bb = ((const float4*)b)[fq];
    float4 acc0 = bb, acc1 = bb;

#pragma unroll 8
    for (int k0 = 0; k0 < D_IN; k0 += 4) {
        float4 w0 = W4[(k0 + 0) * 16 + fq];
        float4 w1 = W4[(k0 + 1) * 16 + fq];
        float4 w2 = W4[(k0 + 2) * 16 + fq];
        float4 w3 = W4[(k0 + 3) * 16 + fq];
        float4 xa = *(const float4*)&xs[slot][k0];
        float4 xb = *(const float4*)&xs[slot + 16][k0];
        acc0 = fma4(xa.x, w0, acc0); acc0 = fma4(xa.y, w1, acc0);
        acc0 = fma4(xa.z, w2, acc0); acc0 = fma4(xa.w, w3, acc0);
        acc1 = fma4(xb.x, w0, acc1); acc1 = fma4(xb.y, w1, acc1);
        acc1 = fma4(xb.z, w2, acc1); acc1 = fma4(xb.w, w3, acc1);
    }

    float4* out4 = (float4*)out;
    int na = nb0 + slot, nbn = nb0 + slot + 16;
    if (na < N_NODES) {
        float4 r = make_float4(fmaxf(acc0.x, 0.f), fmaxf(acc0.y, 0.f),
                               fmaxf(acc0.z, 0.f), fmaxf(acc0.w, 0.f));
        out4[(size_t)na * 16 + fq] = r;
    }
    if (nbn < N_NODES) {
        float4 r = make_float4(fmaxf(acc1.x, 0.f), fmaxf(acc1.y, 0.f),
                               fmaxf(acc1.z, 0.f), fmaxf(acc1.w, 0.f));
        out4[(size_t)nbn * 16 + fq] = r;
    }
}

// ---------------------------------------------------------------------------
// A: per-chunk bucket histogram in LDS -> hblk[blk][bucket]. No global atomics.
// ---------------------------------------------------------------------------
__global__ __launch_bounds__(256)
void bucket_hist_kernel(const int* __restrict__ receivers,
                        int* __restrict__ hblk) {
    __shared__ int h[NBUCK];
    const int tid = threadIdx.x, blk = blockIdx.x;
    for (int j = tid; j < NBUCK; j += 256) h[j] = 0;
    __syncthreads();
    const int4* r4 = (const int4*)receivers + (size_t)blk * I4PB;
    for (int i = tid; i < I4PB; i += 256) {
        int4 r = r4[i];
        atomicAdd(&h[r.x / NPB], 1);
        atomicAdd(&h[r.y / NPB], 1);
        atomicAdd(&h[r.z / NPB], 1);
        atomicAdd(&h[r.w / NPB], 1);
    }
    __syncthreads();
    int* dst = hblk + (size_t)blk * NBUCK;
    for (int j = tid; j < NBUCK; j += 256) dst[j] = h[j];
}

// ---------------------------------------------------------------------------
// S: one block. Per-bucket totals -> exclusive scan -> bbase[0..NBUCK];
// rewrite hblk[blk][b] in place to each chunk's absolute write base.
// ---------------------------------------------------------------------------
__global__ __launch_bounds__(1024)
void bucket_scan_kernel(int* __restrict__ hblk, int* __restrict__ bbase) {
    __shared__ int sums[1024];
    const int t = threadIdx.x;
    int cnt = 0;
    if (t < NBUCK)
        for (int blk = 0; blk < NBLK; ++blk) cnt += hblk[blk * NBUCK + t];
    sums[t] = cnt;
    __syncthreads();
    for (int d = 1; d < 1024; d <<= 1) {
        int v = (t >= d) ? sums[t - d] : 0;
        __syncthreads();
        sums[t] += v;
        __syncthreads();
    }
    if (t < NBUCK) {
        int base = sums[t] - cnt;        // exclusive
        bbase[t] = base;
        if (t == NBUCK - 1) bbase[NBUCK] = sums[t];   // == N_EDGES
        int run = base;
        for (int blk = 0; blk < NBLK; ++blk) {
            int idx = blk * NBUCK + t;
            int c = hblk[idx];
            hblk[idx] = run;
            run += c;
        }
    }
}

// ---------------------------------------------------------------------------
// B: scatter packed (r_local<<17 | sender) into bucket-sorted order using
// LDS cursors (per-block private ranges -> sequential, write-combinable
// global stores; zero global returning atomics).
// ---------------------------------------------------------------------------
__global__ __launch_bounds__(256)
void bucket_fill_kernel(const int* __restrict__ senders,
                        const int* __restrict__ receivers,
                        const int* __restrict__ hblk,
                        unsigned int* __restrict__ packed) {
    __shared__ int cur[NBUCK];
    const int tid = threadIdx.x, blk = blockIdx.x;
    const int* src = hblk + (size_t)blk * NBUCK;
    for (int j = tid; j < NBUCK; j += 256) cur[j] = src[j];
    __syncthreads();
    const int4* r4 = (const int4*)receivers + (size_t)blk * I4PB;
    const int4* s4 = (const int4*)senders   + (size_t)blk * I4PB;
    for (int i = tid; i < I4PB; i += 256) {
        int4 r = r4[i];
        int4 s = s4[i];
        int b, rl, pos;
        b = r.x / NPB; rl = r.x - b * NPB; pos = atomicAdd(&cur[b], 1);
        packed[pos] = ((unsigned)rl << 17) | (unsigned)s.x;
        b = r.y / NPB; rl = r.y - b * NPB; pos = atomicAdd(&cur[b], 1);
        packed[pos] = ((unsigned)rl << 17) | (unsigned)s.y;
        b = r.z / NPB; rl = r.z - b * NPB; pos = atomicAdd(&cur[b], 1);
        packed[pos] = ((unsigned)rl << 17) | (unsigned)s.z;
        b = r.w / NPB; rl = r.w - b * NPB; pos = atomicAdd(&cur[b], 1);
        packed[pos] = ((unsigned)rl << 17) | (unsigned)s.w;
    }
}

// ---------------------------------------------------------------------------
// C: bucketed scatter-max entirely in LDS. One block per bucket; 49x64 agg
// slice in LDS; wave = one edge row (lane = feature), 4 edges in flight.
// LDS atomics are exact for post-relu non-negative floats (uint ordering);
// zero-init == reference's empty-segment->0. agg written once, coalesced.
// ---------------------------------------------------------------------------
__global__ __launch_bounds__(256)
void bucket_max_kernel(const float* __restrict__ projR,
                       const int* __restrict__ bbase,
                       const unsigned int* __restrict__ packed,
                       float* __restrict__ agg) {
    __shared__ unsigned int aggloc[NPB * D_EDGE];   // 12544 B
    const int tid  = threadIdx.x;
    const int b    = blockIdx.x;
    const int lane = tid & 63;
    const int wid  = tid >> 6;
    for (int i = tid; i < NPB * D_EDGE; i += 256) aggloc[i] = 0u;
    __syncthreads();

    const int beg = bbase[b], end = bbase[b + 1];
    for (int e0 = beg + wid * 4; e0 < end; e0 += 16) {
        int m = end - e0; if (m > 4) m = 4;
        unsigned pk0 = packed[e0], pk1 = 0, pk2 = 0, pk3 = 0;
        if (m > 1) pk1 = packed[e0 + 1];
        if (m > 2) pk2 = packed[e0 + 2];
        if (m > 3) pk3 = packed[e0 + 3];
        float v0 = projR[(size_t)(pk0 & 0x1FFFF) * D_EDGE + lane];
        float v1 = 0.f, v2 = 0.f, v3 = 0.f;
        if (m > 1) v1 = projR[(size_t)(pk1 & 0x1FFFF) * D_EDGE + lane];
        if (m > 2) v2 = projR[(size_t)(pk2 & 0x1FFFF) * D_EDGE + lane];
        if (m > 3) v3 = projR[(size_t)(pk3 & 0x1FFFF) * D_EDGE + lane];
        atomicMax(&aggloc[(pk0 >> 17) * D_EDGE + lane], __float_as_uint(v0));
        if (m > 1) atomicMax(&aggloc[(pk1 >> 17) * D_EDGE + lane], __float_as_uint(v1));
        if (m > 2) atomicMax(&aggloc[(pk2 >> 17) * D_EDGE + lane], __float_as_uint(v2));
        if (m > 3) atomicMax(&aggloc[(pk3 >> 17) * D_EDGE + lane], __float_as_uint(v3));
    }
    __syncthreads();

    const int n0 = b * NPB;
    int nN = N_NODES - n0; if (nN > NPB) nN = NPB;
    const int total = nN * D_EDGE;
    for (int i = tid; i < total; i += 256)
        agg[(size_t)n0 * D_EDGE + i] = __uint_as_float(aggloc[i]);
}

// ---------------------------------------------------------------------------
// Kernel 3: out = x @ W_gn + agg @ W_gin + (b_gn + b_gin)   [N_NODES, 128]
// ---------------------------------------------------------------------------
__global__ __launch_bounds__(256)
void node_out_kernel(const float* __restrict__ x,     // [N][128]
                     const float* __restrict__ W_gn,  // [128][128]
                     const float* __restrict__ b_gn,  // [128]
                     const float* __restrict__ agg,   // [N][64]
                     const float* __restrict__ W_gin, // [64][128]
                     const float* __restrict__ b_gin, // [128]
                     float* __restrict__ out) {       // [N][128]
    __shared__ float xs[NB][D_IN + 4];
    __shared__ float as_[NB][D_EDGE + 4];
    const int tid = threadIdx.x;
    const int nb0 = blockIdx.x * NB;

    const float4* xv = (const float4*)x;
    for (int i = tid; i < NB * 32; i += 256) {
        int nl = i >> 5, c = i & 31;
        int n = nb0 + nl;
        float4 v = make_float4(0.f, 0.f, 0.f, 0.f);
        if (n < N_NODES) v = xv[(size_t)n * 32 + c];
        *(float4*)&xs[nl][c * 4] = v;
    }
    const float4* av = (const float4*)agg;
    for (int i = tid; i < NB * 16; i += 256) {
        int nl = i >> 4, c = i & 15;
        int n = nb0 + nl;
        float4 v = make_float4(0.f, 0.f, 0.f, 0.f);
        if (n < N_NODES) v = av[(size_t)n * 16 + c];
        *(float4*)&as_[nl][c * 4] = v;
    }
    __syncthreads();

    const int fq = tid & 31;
    const int slot = tid >> 5;
    const float4* Wg4 = (const float4*)W_gn;
    const float4* Wi4 = (const float4*)W_gin;
    float4 bb = ((const float4*)b_gn)[fq];
    float4 bi = ((const float4*)b_gin)[fq];
    bb.x += bi.x; bb.y += bi.y; bb.z += bi.z; bb.w += bi.w;
    float4 acc0 = bb, acc1 = bb, acc2 = bb, acc3 = bb;

#pragma unroll 4
    for (int k0 = 0; k0 < D_IN; k0 += 4) {
        float4 w0 = Wg4[(k0 + 0) * 32 + fq];
        float4 w1 = Wg4[(k0 + 1) * 32 + fq];
        float4 w2 = Wg4[(k0 + 2) * 32 + fq];
        float4 w3 = Wg4[(k0 + 3) * 32 + fq];
        float4 x0 = *(const float4*)&xs[slot][k0];
        float4 x1 = *(const float4*)&xs[slot + 8][k0];
        float4 x2 = *(const float4*)&xs[slot + 16][k0];
        float4 x3 = *(const float4*)&xs[slot + 24][k0];
        acc0 = fma4(x0.x, w0, acc0); acc0 = fma4(x0.y, w1, acc0);
        acc0 = fma4(x0.z, w2, acc0); acc0 = fma4(x0.w, w3, acc0);
        acc1 = fma4(x1.x, w0, acc1); acc1 = fma4(x1.y, w1, acc1);
        acc1 = fma4(x1.z, w2, acc1); acc1 = fma4(x1.w, w3, acc1);
        acc2 = fma4(x2.x, w0, acc2); acc2 = fma4(x2.y, w1, acc2);
        acc2 = fma4(x2.z, w2, acc2); acc2 = fma4(x2.w, w3, acc2);
        acc3 = fma4(x3.x, w0, acc3); acc3 = fma4(x3.y, w1, acc3);
        acc3 = fma4(x3.z, w2, acc3); acc3 = fma4(x3.w, w3, acc3);
    }

#pragma unroll 4
    for (int k0 = 0; k0 < D_EDGE; k0 += 4) {
        float4 w0 = Wi4[(k0 + 0) * 32 + fq];
        float4 w1 = Wi4[(k0 + 1) * 32 + fq];
        float4 w2 = Wi4[(k0 + 2) * 32 + fq];
        float4 w3 = Wi4[(k0 + 3) * 32 + fq];
        float4 x0 = *(const float4*)&as_[slot][k0];
        float4 x1 = *(const float4*)&as_[slot + 8][k0];
        float4 x2 = *(const float4*)&as_[slot + 16][k0];
        float4 x3 = *(const float4*)&as_[slot + 24][k0];
        acc0 = fma4(x0.x, w0, acc0); acc0 = fma4(x0.y, w1, acc0);
        acc0 = fma4(x0.z, w2, acc0); acc0 = fma4(x0.w, w3, acc0);
        acc1 = fma4(x1.x, w0, acc1); acc1 = fma4(x1.y, w1, acc1);
        acc1 = fma4(x1.z, w2, acc1); acc1 = fma4(x1.w, w3, acc1);
        acc2 = fma4(x2.x, w0, acc2); acc2 = fma4(x2.y, w1, acc2);
        acc2 = fma4(x2.z, w2, acc2); acc2 = fma4(x2.w, w3, acc2);
        acc3 = fma4(x3.x, w0, acc3); acc3 = fma4(x3.y, w1, acc3);
        acc3 = fma4(x3.z, w2, acc3); acc3 = fma4(x3.w, w3, acc3);
    }

    float4* out4 = (float4*)out;
    int n0 = nb0 + slot;
    if (n0 < N_NODES)      out4[(size_t)n0 * 32 + fq]        = acc0;
    if (n0 + 8 < N_NODES)  out4[(size_t)(n0 + 8) * 32 + fq]  = acc1;
    if (n0 + 16 < N_NODES) out4[(size_t)(n0 + 16) * 32 + fq] = acc2;
    if (n0 + 24 < N_NODES) out4[(size_t)(n0 + 24) * 32 + fq] = acc3;
}

// ---------------------------------------------------------------------------
extern "C" void kernel_launch(void* const* d_in, const int* in_sizes, int n_in,
                              void* d_out, int out_size, void* d_ws, size_t ws_size,
                              hipStream_t stream) {
    const float* node_features = (const float*)d_in[0];
    const float* W_fs          = (const float*)d_in[1];
    const float* b_fs          = (const float*)d_in[2];
    const float* W_gn          = (const float*)d_in[3];
    const float* b_gn          = (const float*)d_in[4];
    const float* W_gin         = (const float*)d_in[5];
    const float* b_gin         = (const float*)d_in[6];
    const int*   senders       = (const int*)d_in[7];
    const int*   receivers     = (const int*)d_in[8];
    float* out = (float*)d_out;

    // workspace layout (16B-aligned slices), ~31.6 MiB total
    char* p = (char*)d_ws;
    float*        projR  = (float*)p;        p += (size_t)N_NODES * D_EDGE * 4;  // 12.8 MB
    float*        agg    = (float*)p;        p += (size_t)N_NODES * D_EDGE * 4;  // 12.8 MB
    int*          hblk   = (int*)p;          p += (size_t)NBLK * NBUCK * 4;      // 523 KB
    int*          bbase  = (int*)p;          p += 4096;                          // NBUCK+1 ints
    unsigned int* packed = (unsigned int*)p; p += (size_t)N_EDGES * 4;           // 6.4 MB

    {   // proj+relu
        int grid = (N_NODES + NB - 1) / NB;
        proj_relu_kernel<<<grid, 256, 0, stream>>>(node_features, W_fs, b_fs, projR);
    }
    bucket_hist_kernel<<<NBLK, 256, 0, stream>>>(receivers, hblk);
    bucket_scan_kernel<<<1, 1024, 0, stream>>>(hblk, bbase);
    bucket_fill_kernel<<<NBLK, 256, 0, stream>>>(senders, receivers, hblk, packed);
    bucket_max_kernel<<<NBUCK, 256, 0, stream>>>(projR, bbase, packed, agg);
    {   // final GEMM
        int grid = (N_NODES + NB - 1) / NB;
        node_out_kernel<<<grid, 256, 0, stream>>>(node_features, W_gn, b_gn,
                                                  agg, W_gin, b_gin, out);
    }
}

// Round 12
// 311.025 us; speedup vs baseline: 1.6968x; 1.0706x over previous
//
#include <hip/hip_runtime.h>

#define N_NODES 50000
#define N_EDGES 1600000
#define D_IN    128
#define D_EDGE  64
#define D_NODE  128
#define NB      32        // nodes per block in GEMM kernels

#define NPB     49        // nodes per bucket
#define NBUCK   1021      // ceil(50000/49); bucket 1020 holds 20 nodes
#define NBLK    128       // edge-chunking blocks for hist/fill
#define I4PB    (N_EDGES / NBLK / 4)   // 3125 int4 loads per chunk

__device__ __forceinline__ float4 fma4(float s, float4 w, float4 a) {
    a.x = fmaf(s, w.x, a.x); a.y = fmaf(s, w.y, a.y);
    a.z = fmaf(s, w.z, a.z); a.w = fmaf(s, w.w, a.w);
    return a;
}

// ---------------------------------------------------------------------------
// Kernel 1: projR = relu(x @ W_fs + b_fs)   [N_NODES, 64]
// ---------------------------------------------------------------------------
__global__ __launch_bounds__(256)
void proj_relu_kernel(const float* __restrict__ x,
                      const float* __restrict__ W,   // [128][64]
                      const float* __restrict__ b,   // [64]
                      float* __restrict__ out) {     // [N][64]
    __shared__ float xs[NB][D_IN + 4];
    const int tid = threadIdx.x;
    const int nb0 = blockIdx.x * NB;

    const float4* xv = (const float4*)x;
    for (int i = tid; i < NB * 32; i += 256) {
        int nl = i >> 5, c = i & 31;
        int n = nb0 + nl;
        float4 v = make_float4(0.f, 0.f, 0.f, 0.f);
        if (n < N_NODES) v = xv[(size_t)n * 32 + c];
        *(float4*)&xs[nl][c * 4] = v;
    }
    __syncthreads();

    const int fq = tid & 15;
    const int slot = tid >> 4;
    const float4* W4 = (const float4*)W;
    float4 bb = ((const float4*)b)[fq];
    float4 acc0 = bb, acc1 = bb;

#pragma unroll 8
    for (int k0 = 0; k0 < D_IN; k0 += 4) {
        float4 w0 = W4[(k0 + 0) * 16 + fq];
        float4 w1 = W4[(k0 + 1) * 16 + fq];
        float4 w2 = W4[(k0 + 2) * 16 + fq];
        float4 w3 = W4[(k0 + 3) * 16 + fq];
        float4 xa = *(const float4*)&xs[slot][k0];
        float4 xb = *(const float4*)&xs[slot + 16][k0];
        acc0 = fma4(xa.x, w0, acc0); acc0 = fma4(xa.y, w1, acc0);
        acc0 = fma4(xa.z, w2, acc0); acc0 = fma4(xa.w, w3, acc0);
        acc1 = fma4(xb.x, w0, acc1); acc1 = fma4(xb.y, w1, acc1);
        acc1 = fma4(xb.z, w2, acc1); acc1 = fma4(xb.w, w3, acc1);
    }

    float4* out4 = (float4*)out;
    int na = nb0 + slot, nbn = nb0 + slot + 16;
    if (na < N_NODES) {
        float4 r = make_float4(fmaxf(acc0.x, 0.f), fmaxf(acc0.y, 0.f),
                               fmaxf(acc0.z, 0.f), fmaxf(acc0.w, 0.f));
        out4[(size_t)na * 16 + fq] = r;
    }
    if (nbn < N_NODES) {
        float4 r = make_float4(fmaxf(acc1.x, 0.f), fmaxf(acc1.y, 0.f),
                               fmaxf(acc1.z, 0.f), fmaxf(acc1.w, 0.f));
        out4[(size_t)nbn * 16 + fq] = r;
    }
}

// ---------------------------------------------------------------------------
// A: per-chunk bucket histogram in LDS -> hblk[blk][bucket]. No global atomics.
// ---------------------------------------------------------------------------
__global__ __launch_bounds__(256)
void bucket_hist_kernel(const int* __restrict__ receivers,
                        int* __restrict__ hblk) {
    __shared__ int h[NBUCK];
    const int tid = threadIdx.x, blk = blockIdx.x;
    for (int j = tid; j < NBUCK; j += 256) h[j] = 0;
    __syncthreads();
    const int4* r4 = (const int4*)receivers + (size_t)blk * I4PB;
    for (int i = tid; i < I4PB; i += 256) {
        int4 r = r4[i];
        atomicAdd(&h[r.x / NPB], 1);
        atomicAdd(&h[r.y / NPB], 1);
        atomicAdd(&h[r.z / NPB], 1);
        atomicAdd(&h[r.w / NPB], 1);
    }
    __syncthreads();
    int* dst = hblk + (size_t)blk * NBUCK;
    for (int j = tid; j < NBUCK; j += 256) dst[j] = h[j];
}

// ---------------------------------------------------------------------------
// S: one block. Per-bucket totals -> exclusive scan -> bbase[0..NBUCK];
// rewrite hblk[blk][b] in place to each chunk's absolute write base.
// ---------------------------------------------------------------------------
__global__ __launch_bounds__(1024)
void bucket_scan_kernel(int* __restrict__ hblk, int* __restrict__ bbase) {
    __shared__ int sums[1024];
    const int t = threadIdx.x;
    int cnt = 0;
    if (t < NBUCK)
        for (int blk = 0; blk < NBLK; ++blk) cnt += hblk[blk * NBUCK + t];
    sums[t] = cnt;
    __syncthreads();
    for (int d = 1; d < 1024; d <<= 1) {
        int v = (t >= d) ? sums[t - d] : 0;
        __syncthreads();
        sums[t] += v;
        __syncthreads();
    }
    if (t < NBUCK) {
        int base = sums[t] - cnt;        // exclusive
        bbase[t] = base;
        if (t == NBUCK - 1) bbase[NBUCK] = sums[t];   // == N_EDGES
        int run = base;
        for (int blk = 0; blk < NBLK; ++blk) {
            int idx = blk * NBUCK + t;
            int c = hblk[idx];
            hblk[idx] = run;
            run += c;
        }
    }
}

// ---------------------------------------------------------------------------
// B: scatter packed (r_local<<17 | sender) into bucket-sorted order using
// LDS cursors (per-block private ranges -> sequential, write-combinable
// global stores; zero global returning atomics).
// ---------------------------------------------------------------------------
__global__ __launch_bounds__(256)
void bucket_fill_kernel(const int* __restrict__ senders,
                        const int* __restrict__ receivers,
                        const int* __restrict__ hblk,
                        unsigned int* __restrict__ packed) {
    __shared__ int cur[NBUCK];
    const int tid = threadIdx.x, blk = blockIdx.x;
    const int* src = hblk + (size_t)blk * NBUCK;
    for (int j = tid; j < NBUCK; j += 256) cur[j] = src[j];
    __syncthreads();
    const int4* r4 = (const int4*)receivers + (size_t)blk * I4PB;
    const int4* s4 = (const int4*)senders   + (size_t)blk * I4PB;
    for (int i = tid; i < I4PB; i += 256) {
        int4 r = r4[i];
        int4 s = s4[i];
        int b, rl, pos;
        b = r.x / NPB; rl = r.x - b * NPB; pos = atomicAdd(&cur[b], 1);
        packed[pos] = ((unsigned)rl << 17) | (unsigned)s.x;
        b = r.y / NPB; rl = r.y - b * NPB; pos = atomicAdd(&cur[b], 1);
        packed[pos] = ((unsigned)rl << 17) | (unsigned)s.y;
        b = r.z / NPB; rl = r.z - b * NPB; pos = atomicAdd(&cur[b], 1);
        packed[pos] = ((unsigned)rl << 17) | (unsigned)s.z;
        b = r.w / NPB; rl = r.w - b * NPB; pos = atomicAdd(&cur[b], 1);
        packed[pos] = ((unsigned)rl << 17) | (unsigned)s.w;
    }
}

// ---------------------------------------------------------------------------
// C: bucketed scatter-max entirely in LDS.
// R10 fix: 512 threads (8 waves) per block + 8 edges in flight per wave.
// Grid 1021 blocks -> 4 blocks/CU x 8 waves = 32 waves/CU (100% occupancy;
// was 50% cap with 4-wave blocks). In-flight gathers per CU: 64 -> 256.
// LDS atomics exact for post-relu non-negative floats (uint ordering);
// zero-init == reference's empty-segment->0. agg written once, coalesced.
// ---------------------------------------------------------------------------
__global__ __launch_bounds__(512)
void bucket_max_kernel(const float* __restrict__ projR,
                       const int* __restrict__ bbase,
                       const unsigned int* __restrict__ packed,
                       float* __restrict__ agg) {
    __shared__ unsigned int aggloc[NPB * D_EDGE];   // 12544 B
    const int tid  = threadIdx.x;
    const int b    = blockIdx.x;
    const int lane = tid & 63;
    const int wid  = tid >> 6;                      // 0..7
    for (int i = tid; i < NPB * D_EDGE; i += 512) aggloc[i] = 0u;
    __syncthreads();

    const int beg = bbase[b], end = bbase[b + 1];
    for (int e0 = beg + wid * 8; e0 < end; e0 += 64) {
        int m = end - e0; if (m > 8) m = 8;
        unsigned pk[8];
        float v[8];
#pragma unroll
        for (int j = 0; j < 8; ++j)
            pk[j] = (j < m) ? packed[e0 + j] : 0u;
#pragma unroll
        for (int j = 0; j < 8; ++j)
            v[j] = (j < m) ? projR[(size_t)(pk[j] & 0x1FFFF) * D_EDGE + lane] : 0.f;
#pragma unroll
        for (int j = 0; j < 8; ++j)
            if (j < m)
                atomicMax(&aggloc[(pk[j] >> 17) * D_EDGE + lane],
                          __float_as_uint(v[j]));
    }
    __syncthreads();

    const int n0 = b * NPB;
    int nN = N_NODES - n0; if (nN > NPB) nN = NPB;
    const int total = nN * D_EDGE;
    for (int i = tid; i < total; i += 512)
        agg[(size_t)n0 * D_EDGE + i] = __uint_as_float(aggloc[i]);
}

// ---------------------------------------------------------------------------
// Kernel 3: out = x @ W_gn + agg @ W_gin + (b_gn + b_gin)   [N_NODES, 128]
// ---------------------------------------------------------------------------
__global__ __launch_bounds__(256)
void node_out_kernel(const float* __restrict__ x,     // [N][128]
                     const float* __restrict__ W_gn,  // [128][128]
                     const float* __restrict__ b_gn,  // [128]
                     const float* __restrict__ agg,   // [N][64]
                     const float* __restrict__ W_gin, // [64][128]
                     const float* __restrict__ b_gin, // [128]
                     float* __restrict__ out) {       // [N][128]
    __shared__ float xs[NB][D_IN + 4];
    __shared__ float as_[NB][D_EDGE + 4];
    const int tid = threadIdx.x;
    const int nb0 = blockIdx.x * NB;

    const float4* xv = (const float4*)x;
    for (int i = tid; i < NB * 32; i += 256) {
        int nl = i >> 5, c = i & 31;
        int n = nb0 + nl;
        float4 v = make_float4(0.f, 0.f, 0.f, 0.f);
        if (n < N_NODES) v = xv[(size_t)n * 32 + c];
        *(float4*)&xs[nl][c * 4] = v;
    }
    const float4* av = (const float4*)agg;
    for (int i = tid; i < NB * 16; i += 256) {
        int nl = i >> 4, c = i & 15;
        int n = nb0 + nl;
        float4 v = make_float4(0.f, 0.f, 0.f, 0.f);
        if (n < N_NODES) v = av[(size_t)n * 16 + c];
        *(float4*)&as_[nl][c * 4] = v;
    }
    __syncthreads();

    const int fq = tid & 31;
    const int slot = tid >> 5;
    const float4* Wg4 = (const float4*)W_gn;
    const float4* Wi4 = (const float4*)W_gin;
    float4 bb = ((const float4*)b_gn)[fq];
    float4 bi = ((const float4*)b_gin)[fq];
    bb.x += bi.x; bb.y += bi.y; bb.z += bi.z; bb.w += bi.w;
    float4 acc0 = bb, acc1 = bb, acc2 = bb, acc3 = bb;

#pragma unroll 4
    for (int k0 = 0; k0 < D_IN; k0 += 4) {
        float4 w0 = Wg4[(k0 + 0) * 32 + fq];
        float4 w1 = Wg4[(k0 + 1) * 32 + fq];
        float4 w2 = Wg4[(k0 + 2) * 32 + fq];
        float4 w3 = Wg4[(k0 + 3) * 32 + fq];
        float4 x0 = *(const float4*)&xs[slot][k0];
        float4 x1 = *(const float4*)&xs[slot + 8][k0];
        float4 x2 = *(const float4*)&xs[slot + 16][k0];
        float4 x3 = *(const float4*)&xs[slot + 24][k0];
        acc0 = fma4(x0.x, w0, acc0); acc0 = fma4(x0.y, w1, acc0);
        acc0 = fma4(x0.z, w2, acc0); acc0 = fma4(x0.w, w3, acc0);
        acc1 = fma4(x1.x, w0, acc1); acc1 = fma4(x1.y, w1, acc1);
        acc1 = fma4(x1.z, w2, acc1); acc1 = fma4(x1.w, w3, acc1);
        acc2 = fma4(x2.x, w0, acc2); acc2 = fma4(x2.y, w1, acc2);
        acc2 = fma4(x2.z, w2, acc2); acc2 = fma4(x2.w, w3, acc2);
        acc3 = fma4(x3.x, w0, acc3); acc3 = fma4(x3.y, w1, acc3);
        acc3 = fma4(x3.z, w2, acc3); acc3 = fma4(x3.w, w3, acc3);
    }

#pragma unroll 4
    for (int k0 = 0; k0 < D_EDGE; k0 += 4) {
        float4 w0 = Wi4[(k0 + 0) * 32 + fq];
        float4 w1 = Wi4[(k0 + 1) * 32 + fq];
        float4 w2 = Wi4[(k0 + 2) * 32 + fq];
        float4 w3 = Wi4[(k0 + 3) * 32 + fq];
        float4 x0 = *(const float4*)&as_[slot][k0];
        float4 x1 = *(const float4*)&as_[slot + 8][k0];
        float4 x2 = *(const float4*)&as_[slot + 16][k0];
        float4 x3 = *(const float4*)&as_[slot + 24][k0];
        acc0 = fma4(x0.x, w0, acc0); acc0 = fma4(x0.y, w1, acc0);
        acc0 = fma4(x0.z, w2, acc0); acc0 = fma4(x0.w, w3, acc0);
        acc1 = fma4(x1.x, w0, acc1); acc1 = fma4(x1.y, w1, acc1);
        acc1 = fma4(x1.z, w2, acc1); acc1 = fma4(x1.w, w3, acc1);
        acc2 = fma4(x2.x, w0, acc2); acc2 = fma4(x2.y, w1, acc2);
        acc2 = fma4(x2.z, w2, acc2); acc2 = fma4(x2.w, w3, acc2);
        acc3 = fma4(x3.x, w0, acc3); acc3 = fma4(x3.y, w1, acc3);
        acc3 = fma4(x3.z, w2, acc3); acc3 = fma4(x3.w, w3, acc3);
    }

    float4* out4 = (float4*)out;
    int n0 = nb0 + slot;
    if (n0 < N_NODES)      out4[(size_t)n0 * 32 + fq]        = acc0;
    if (n0 + 8 < N_NODES)  out4[(size_t)(n0 + 8) * 32 + fq]  = acc1;
    if (n0 + 16 < N_NODES) out4[(size_t)(n0 + 16) * 32 + fq] = acc2;
    if (n0 + 24 < N_NODES) out4[(size_t)(n0 + 24) * 32 + fq] = acc3;
}

// ---------------------------------------------------------------------------
extern "C" void kernel_launch(void* const* d_in, const int* in_sizes, int n_in,
                              void* d_out, int out_size, void* d_ws, size_t ws_size,
                              hipStream_t stream) {
    const float* node_features = (const float*)d_in[0];
    const float* W_fs          = (const float*)d_in[1];
    const float* b_fs          = (const float*)d_in[2];
    const float* W_gn          = (const float*)d_in[3];
    const float* b_gn          = (const float*)d_in[4];
    const float* W_gin         = (const float*)d_in[5];
    const float* b_gin         = (const float*)d_in[6];
    const int*   senders       = (const int*)d_in[7];
    const int*   receivers     = (const int*)d_in[8];
    float* out = (float*)d_out;

    // workspace layout (16B-aligned slices), ~31.6 MiB total
    char* p = (char*)d_ws;
    float*        projR  = (float*)p;        p += (size_t)N_NODES * D_EDGE * 4;  // 12.8 MB
    float*        agg    = (float*)p;        p += (size_t)N_NODES * D_EDGE * 4;  // 12.8 MB
    int*          hblk   = (int*)p;          p += (size_t)NBLK * NBUCK * 4;      // 523 KB
    int*          bbase  = (int*)p;          p += 4096;                          // NBUCK+1 ints
    unsigned int* packed = (unsigned int*)p; p += (size_t)N_EDGES * 4;           // 6.4 MB

    {   // proj+relu
        int grid = (N_NODES + NB - 1) / NB;
        proj_relu_kernel<<<grid, 256, 0, stream>>>(node_features, W_fs, b_fs, projR);
    }
    bucket_hist_kernel<<<NBLK, 256, 0, stream>>>(receivers, hblk);
    bucket_scan_kernel<<<1, 1024, 0, stream>>>(hblk, bbase);
    bucket_fill_kernel<<<NBLK, 256, 0, stream>>>(senders, receivers, hblk, packed);
    bucket_max_kernel<<<NBUCK, 512, 0, stream>>>(projR, bbase, packed, agg);
    {   // final GEMM
        int grid = (N_NODES + NB - 1) / NB;
        node_out_kernel<<<grid, 256, 0, stream>>>(node_features, W_gn, b_gn,
                                                  agg, W_gin, b_gin, out);
    }
}